// Round 8
// baseline (174.371 us; speedup 1.0000x reference)
//
#include <hip/hip_runtime.h>

typedef unsigned short u16;
typedef unsigned long long u64;
typedef float floatx4 __attribute__((ext_vector_type(4)));
typedef short shortx8 __attribute__((ext_vector_type(8)));

__device__ inline u16 f2bf(float f) {
  unsigned u = __float_as_uint(f);
  u += 0x7fffu + ((u >> 16) & 1u);
  return (u16)(u >> 16);
}

// async global->LDS, 16B per lane (wave-uniform LDS base + lane*16).
__device__ __forceinline__ void gl16(const u16* g, const u16* l) {
  __builtin_amdgcn_global_load_lds(
      (const __attribute__((address_space(1))) unsigned int*)(u64)(const void*)g,
      (__attribute__((address_space(3))) unsigned int*)(unsigned)(u64)(const void*)l,
      16, 0, 0);
}

// ---------------------------------------------------------------------------
// fp32 -> bf16 conversion (round-2 verbatim)
// ushort offsets: qb 0 | vb 4194304 | w1cat 8388608 | w3cat 8912896 |
// wob 9437184 | w2b0p 9699328 (128x512) | w2b1p 9764864 (256x512) | end 9895936
// ---------------------------------------------------------------------------
__global__ __launch_bounds__(256) void convert_all(
    const float* __restrict__ q, const float* __restrict__ v,
    const float* __restrict__ w10, const float* __restrict__ w11,
    const float* __restrict__ w30, const float* __restrict__ w31,
    const float* __restrict__ wo, const float* __restrict__ w20,
    const float* __restrict__ w21, u16* __restrict__ base) {
  size_t e = ((size_t)blockIdx.x * 256 + threadIdx.x) * 4;
  const float* src;
  u16* dst;
  size_t le;
  unsigned prows;
  if (e < 4194304ull)      { src = q;   dst = base;            le = e;            prows = 0x7fffffffu; }
  else if (e < 8388608ull) { src = v;   dst = base + 4194304;  le = e - 4194304;  prows = 0x7fffffffu; }
  else if (e < 8650752ull) { src = w10; dst = base + 8388608;  le = e - 8388608;  prows = 0x7fffffffu; }
  else if (e < 8912896ull) { src = w11; dst = base + 8650752;  le = e - 8650752;  prows = 0x7fffffffu; }
  else if (e < 9175040ull) { src = w30; dst = base + 8912896;  le = e - 8912896;  prows = 0x7fffffffu; }
  else if (e < 9437184ull) { src = w31; dst = base + 9175040;  le = e - 9175040;  prows = 0x7fffffffu; }
  else if (e < 9699328ull) { src = wo;  dst = base + 9437184;  le = e - 9437184;  prows = 0x7fffffffu; }
  else if (e < 9764864ull) { src = w20; dst = base + 9699328;  le = e - 9699328;  prows = 124; }
  else                     { src = w21; dst = base + 9764864;  le = e - 9764864;  prows = 244; }
  float4 val = make_float4(0.f, 0.f, 0.f, 0.f);
  if ((unsigned)(le >> 9) < prows) val = *(const float4*)(src + le);
  unsigned p0 = (unsigned)f2bf(val.x) | ((unsigned)f2bf(val.y) << 16);
  unsigned p1 = (unsigned)f2bf(val.z) | ((unsigned)f2bf(val.w) << 16);
  *(uint2*)(dst + le) = make_uint2(p0, p1);
}

// ---------------------------------------------------------------------------
// m97-structure GEMM core (round-2 verbatim)
// ---------------------------------------------------------------------------
template <int OUTBF>
__device__ __forceinline__ void gemm_core(
    const u16* __restrict__ A, int lda, const u16* __restrict__ W, int ldw,
    float* __restrict__ Cf, u16* __restrict__ Cb, int ldc, int relu,
    u16* lA, u16* lB) {
  const int tid = threadIdx.x;
  const int wave = tid >> 6, lane = tid & 63;
  const int wm = (wave >> 1) * 64, wn = (wave & 1) * 64;
  const int lr = lane & 15, kq = (lane >> 4) * 8;
  const int sr = lane >> 2, sc = (lane & 3) * 8;

  floatx4 acc[4][4];
#pragma unroll
  for (int i = 0; i < 4; ++i)
#pragma unroll
    for (int j = 0; j < 4; ++j) acc[i][j] = (floatx4){0.f, 0.f, 0.f, 0.f};

  const u16* ga0 = A + (u64)(wave * 32 + sr) * lda + sc;
  const u16* ga1 = A + (u64)(wave * 32 + 16 + sr) * lda + sc;
  const u16* gb0 = W + (u64)(wave * 32 + sr) * ldw + sc;
  const u16* gb1 = W + (u64)(wave * 32 + 16 + sr) * ldw + sc;
  u16* la0 = lA + (wave * 32) * 32;
  u16* la1 = lA + (wave * 32 + 16) * 32;
  u16* lb0 = lB + (wave * 32) * 32;
  u16* lb1 = lB + (wave * 32 + 16) * 32;

  for (int k0 = 0; k0 < 512; k0 += 32) {
    __syncthreads();
    gl16(ga0 + k0, la0);
    gl16(ga1 + k0, la1);
    gl16(gb0 + k0, lb0);
    gl16(gb1 + k0, lb1);
    __syncthreads();
    shortx8 af[4], bf8[4];
#pragma unroll
    for (int i = 0; i < 4; ++i) {
      af[i] = *(const shortx8*)&lA[(wm + i * 16 + lr) * 32 + kq];
      bf8[i] = *(const shortx8*)&lB[(wn + i * 16 + lr) * 32 + kq];
    }
#pragma unroll
    for (int mi = 0; mi < 4; ++mi)
#pragma unroll
      for (int ni = 0; ni < 4; ++ni)
        acc[mi][ni] = __builtin_amdgcn_mfma_f32_16x16x32_bf16(af[mi], bf8[ni], acc[mi][ni], 0, 0, 0);
  }
  const int er = wm + (lane >> 4) * 4;
  const int ec = wn + lr;
#pragma unroll
  for (int mi = 0; mi < 4; ++mi)
#pragma unroll
    for (int ni = 0; ni < 4; ++ni)
#pragma unroll
      for (int r = 0; r < 4; ++r) {
        float vv = acc[mi][ni][r];
        if (relu) vv = fmaxf(vv, 0.f);
        u64 off = (u64)(er + mi * 16 + r) * (u64)ldc + (u64)(ec + ni * 16);
        if (OUTBF) Cb[off] = f2bf(vv);
        else Cf[off] = vv;
      }
}

// fused q/v projection: grid (128, 8). x<64 -> q-half (relu), else v-half.
__global__ __launch_bounds__(256, 2) void k_qv(
    const u16* __restrict__ qb, const u16* __restrict__ vb,
    const u16* __restrict__ w1, const u16* __restrict__ w3,
    u16* __restrict__ rq, u16* __restrict__ vc) {
  __shared__ __align__(16) u16 lA[128 * 32];
  __shared__ __align__(16) u16 lB[128 * 32];
  const int bx = blockIdx.x, bn = blockIdx.y * 128;
  const bool isq = bx < 64;
  const int am = (isq ? bx : bx - 64) * 128;
  const u16* A = (isq ? qb : vb) + (u64)am * 512;
  const u16* W = (isq ? w1 : w3) + (u64)bn * 512;
  u16* Cb = (isq ? rq : vc) + (u64)am * 1024 + bn;
  gemm_core<1>(A, 512, W, 512, nullptr, Cb, 1024, isq ? 1 : 0, lA, lB);
}

// fused logits for both scales: grid (64, 3).
__global__ __launch_bounds__(256, 2) void k_logits(
    const u16* __restrict__ rq, const u16* __restrict__ w20,
    const u16* __restrict__ w21, float* __restrict__ lg) {
  __shared__ __align__(16) u16 lA[128 * 32];
  __shared__ __align__(16) u16 lB[128 * 32];
  const int am = blockIdx.x * 128;
  const int y = blockIdx.y;
  const u16* A = rq + (u64)am * 1024 + (y == 0 ? 0 : 512);
  const u16* W = (y == 0) ? w20 : (w21 + (u64)(y - 1) * 128 * 512);
  float* Cf = lg + (u64)am * 384 + y * 128;
  gemm_core<0>(A, 1024, W, 512, Cf, nullptr, 384, 0, lA, lB);
}

// final projection: grid (64, 4), fp32 out.
__global__ __launch_bounds__(256, 2) void k_final(
    const u16* __restrict__ xb, const u16* __restrict__ wo,
    float* __restrict__ out) {
  __shared__ __align__(16) u16 lA[128 * 32];
  __shared__ __align__(16) u16 lB[128 * 32];
  const int am = blockIdx.x * 128, bn = blockIdx.y * 128;
  gemm_core<0>(xb + (u64)am * 512, 512, wo + (u64)bn * 512, 512,
               out + (u64)am * 512 + bn, nullptr, 512, 0, lA, lB);
}

// ---------------------------------------------------------------------------
// MFMA attention pass, round-8: 2 barriers/pass (was 4).
//  - logits pre-loaded into registers by caller (no global reads inside).
//  - es16 band-complement zeroing fused into the exp phase (cols [0,128) of
//    each row are written exactly once: band cols get exp, the rest zeros;
//    cols >=128 are never read by the MFMA A-frags so stay untouched).
//  - row sums via intra-quad __shfl_xor (threads qq=0..3 of row tt are
//    adjacent lanes of one wave); lane qq==0 writes invsum[tt].
// vT staging unchanged from round 7 (coalesced + XOR swizzle).
// ---------------------------------------------------------------------------
#define VLDT 136
#define ESL 152

template <int CS, int CHUNK>
__device__ __forceinline__ void attn_mfma_pass(
    const float (&lreg)[CHUNK],     // this thread's logits chunk (prefetched)
    const u16* __restrict__ vbh,    // vcat + scale*512 + h*128, row stride 1024
    int bb, int t0, float swv,
    u16* vT, u16* es16, float* invsum, floatx4 (&o)[8]) {
  constexpr int HALF = (CS - 1) / 2;
  constexpr int NW = 64 + CS - 1;  // valid window rows (94 / 124)
  const int tid = threadIdx.x;
  const int wave = tid >> 6, lane = tid & 63;
  const int lr = lane & 15, kq = (lane >> 4) * 8;

  __syncthreads();  // prior consumers done with vT/es16/invsum

  // stage V-window transposed+swizzled; loads coalesced (lane spans d).
#pragma unroll
  for (int it = 0; it < 8; ++it) {
    int idx = it * 256 + tid;
    int r = idx >> 4;              // 0..127
    int d8 = (idx & 15) * 8;       // 0..120
    int t = t0 + r - HALF;
    uint4 u = make_uint4(0u, 0u, 0u, 0u);
    if (r < NW && t >= 0 && t < 2048)
      u = *(const uint4*)&vbh[(u64)(bb + t) * 1024 + d8];
    int sb = (((r >> 3) ^ ((d8 >> 3) & 7)) << 3) + (r & 7);
    u16* wp = &vT[d8 * VLDT + sb];
    const u16* us = (const u16*)&u;
#pragma unroll
    for (int j = 0; j < 8; ++j) wp[j * VLDT] = us[j];
  }

  // exp (from prefetched regs) + complement zeros + quad row-sum
  {
    int tt = tid >> 2, qq = tid & 3;
    u16* row = es16 + tt * ESL;
    const int lo = tt, hi = tt + CS;
#pragma unroll
    for (int j = 0; j < 32; ++j) {
      int x = qq * 32 + j;
      if (x < lo || x >= hi) row[x] = 0;
    }
    float ps = 0.f;
#pragma unroll
    for (int j = 0; j < CHUNK; ++j) {
      int c = qq * CHUNK + j;
      if (c < CS) {
        float ev = __expf(lreg[j]);
        row[lo + c] = f2bf(ev);
        ps += ev;
      }
    }
    ps += __shfl_xor(ps, 1, 64);
    ps += __shfl_xor(ps, 2, 64);
    if (qq == 0) invsum[tt] = swv / ps;
  }
  __syncthreads();

  // MFMA: wave w owns output rows w*16..w*16+15; band limits k-blocks.
  const int kb_lo = (wave * 16) >> 5;
  const int kb_hi = (wave * 16 + 15 + CS - 1) >> 5;
  floatx4 acc[8];
#pragma unroll
  for (int nt = 0; nt < 8; ++nt) acc[nt] = (floatx4){0.f, 0.f, 0.f, 0.f};
  for (int kb = kb_lo; kb <= kb_hi; ++kb) {
    shortx8 af = *(const shortx8*)&es16[(wave * 16 + lr) * ESL + kb * 32 + kq];
    int rb8 = kb * 4 + (lane >> 4);
#pragma unroll
    for (int nt = 0; nt < 8; ++nt) {
      int d_row = nt * 16 + lr;
      int blk = (rb8 ^ ((d_row >> 3) & 7)) << 3;
      shortx8 bf8 = *(const shortx8*)&vT[d_row * VLDT + blk];
      acc[nt] = __builtin_amdgcn_mfma_f32_16x16x32_bf16(af, bf8, acc[nt], 0, 0, 0);
    }
  }
  // fold swv/rowsum, accumulate into persistent o (C-layout rows)
  float invs[4];
#pragma unroll
  for (int rr = 0; rr < 4; ++rr)
    invs[rr] = invsum[wave * 16 + (lane >> 4) * 4 + rr];
#pragma unroll
  for (int nt = 0; nt < 8; ++nt)
#pragma unroll
    for (int rr = 0; rr < 4; ++rr) o[nt][rr] += acc[nt][rr] * invs[rr];
}

__global__ __launch_bounds__(256, 1) void k_attn3(
    const float* __restrict__ lg, const u16* __restrict__ vcat,
    const float* __restrict__ swp, u16* __restrict__ xbw) {
  __shared__ __align__(16) u16 vT[128 * VLDT];
  __shared__ __align__(16) u16 es16[64 * ESL];
  __shared__ float invsum[64];
  const int tid = threadIdx.x;
  const int wave = tid >> 6, lane = tid & 63;
  const int lr = lane & 15;
  const int t0 = blockIdx.x * 64, h = blockIdx.y, b = blockIdx.z;
  const int bb = b * 2048;
  const int m0 = bb + t0;

  // prefetch both scales' logits into registers (issued before any barrier;
  // latency hidden under pass-0 staging). Chunked ownership: thread qq of
  // row tt owns cols [qq*CHUNK, qq*CHUNK+CHUNK) of that row's CS block.
  const int ptt = tid >> 2, pqq = tid & 3;
  float l0[8], l1[16];
  {
    const float* r0 = lg + (u64)(m0 + ptt) * 384 + h * 31 + pqq * 8;
#pragma unroll
    for (int j = 0; j < 8; ++j) l0[j] = r0[j];
    const float* r1 = lg + (u64)(m0 + ptt) * 384 + 128 + h * 61 + pqq * 16;
#pragma unroll
    for (int j = 0; j < 16; ++j) l1[j] = r1[j];
  }

  float a0 = swp[0], a1 = swp[1];
  float mx = fmaxf(a0, a1);
  float e0 = __expf(a0 - mx), e1 = __expf(a1 - mx);
  float inv = 1.f / (e0 + e1);

  floatx4 o[8];
#pragma unroll
  for (int nt = 0; nt < 8; ++nt) o[nt] = (floatx4){0.f, 0.f, 0.f, 0.f};

  attn_mfma_pass<31, 8>(l0, vcat + h * 128, bb, t0, e0 * inv,
                        vT, es16, invsum, o);
  attn_mfma_pass<61, 16>(l1, vcat + 512 + h * 128, bb, t0, e1 * inv,
                         vT, es16, invsum, o);

  // epilogue: stage bf16 output tile in es16 (reuse), then coalesced stores
  __syncthreads();
#pragma unroll
  for (int nt = 0; nt < 8; ++nt)
#pragma unroll
    for (int rr = 0; rr < 4; ++rr) {
      int trow = wave * 16 + (lane >> 4) * 4 + rr;
      es16[trow * ESL + nt * 16 + lr] = f2bf(o[nt][rr]);
    }
  __syncthreads();
#pragma unroll
  for (int rep = 0; rep < 4; ++rep) {
    int idx = rep * 256 + tid;
    int trow = idx >> 4;
    int col8 = (idx & 15) * 8;
    uint4 u = *(const uint4*)&es16[trow * ESL + col8];
    *(uint4*)&xbw[(u64)(m0 + trow) * 512 + h * 128 + col8] = u;
  }
}

// ---------------------------------------------------------------------------
extern "C" void kernel_launch(void* const* d_in, const int* in_sizes, int n_in,
                              void* d_out, int out_size, void* d_ws, size_t ws_size,
                              hipStream_t stream) {
  const float* q   = (const float*)d_in[0];
  const float* v   = (const float*)d_in[2];
  const float* w10 = (const float*)d_in[3];
  const float* w11 = (const float*)d_in[4];
  const float* w20 = (const float*)d_in[5];
  const float* w21 = (const float*)d_in[6];
  const float* w30 = (const float*)d_in[7];
  const float* w31 = (const float*)d_in[8];
  const float* sw  = (const float*)d_in[9];
  const float* wo  = (const float*)d_in[10];
  float* out = (float*)d_out;

  u16* base  = (u16*)d_ws;
  u16* qb    = base;
  u16* vb    = base + 4194304;
  u16* w1cat = base + 8388608;
  u16* w3cat = base + 8912896;
  u16* wob   = base + 9437184;
  u16* w2b0  = base + 9699328;
  u16* w2b1  = base + 9764864;
  char* fb = (char*)d_ws + 19791872;
  float* logitsC = (float*)fb;            // [8192][384]
  u16* rqcat = (u16*)(logitsC + 3145728); // [8192][1024]
  u16* vcat  = rqcat + 8388608;           // [8192][1024]
  u16* xb    = vcat + 8388608;            // [8192][512]
  // total ws use: 74,317,824 bytes

  convert_all<<<dim3(9664), dim3(256), 0, stream>>>(q, v, w10, w11, w30, w31, wo, w20, w21, base);

  dim3 blk(256);
  k_qv<<<dim3(128, 8), blk, 0, stream>>>(qb, vb, w1cat, w3cat, rqcat, vcat);
  k_logits<<<dim3(64, 3), blk, 0, stream>>>(rqcat, w2b0, w2b1, logitsC);
  k_attn3<<<dim3(32, 4, 4), blk, 0, stream>>>(logitsC, vcat, sw, xb);
  k_final<<<dim3(64, 4), blk, 0, stream>>>(xb, wob, out);
}

// Round 9
// 173.381 us; speedup vs baseline: 1.0057x; 1.0057x over previous
//
#include <hip/hip_runtime.h>

typedef unsigned short u16;
typedef unsigned long long u64;
typedef float floatx4 __attribute__((ext_vector_type(4)));
typedef short shortx8 __attribute__((ext_vector_type(8)));

__device__ inline u16 f2bf(float f) {
  unsigned u = __float_as_uint(f);
  u += 0x7fffu + ((u >> 16) & 1u);
  return (u16)(u >> 16);
}

// async global->LDS, 16B per lane (wave-uniform LDS base + lane*16).
__device__ __forceinline__ void gl16(const u16* g, const u16* l) {
  __builtin_amdgcn_global_load_lds(
      (const __attribute__((address_space(1))) unsigned int*)(u64)(const void*)g,
      (__attribute__((address_space(3))) unsigned int*)(unsigned)(u64)(const void*)l,
      16, 0, 0);
}

// ---------------------------------------------------------------------------
// fp32 -> bf16 conversion (round-2 verbatim)
// ushort offsets: qb 0 | vb 4194304 | w1cat 8388608 | w3cat 8912896 |
// wob 9437184 | w2b0p 9699328 (128x512) | w2b1p 9764864 (256x512) | end 9895936
// ---------------------------------------------------------------------------
__global__ __launch_bounds__(256) void convert_all(
    const float* __restrict__ q, const float* __restrict__ v,
    const float* __restrict__ w10, const float* __restrict__ w11,
    const float* __restrict__ w30, const float* __restrict__ w31,
    const float* __restrict__ wo, const float* __restrict__ w20,
    const float* __restrict__ w21, u16* __restrict__ base) {
  size_t e = ((size_t)blockIdx.x * 256 + threadIdx.x) * 4;
  const float* src;
  u16* dst;
  size_t le;
  unsigned prows;
  if (e < 4194304ull)      { src = q;   dst = base;            le = e;            prows = 0x7fffffffu; }
  else if (e < 8388608ull) { src = v;   dst = base + 4194304;  le = e - 4194304;  prows = 0x7fffffffu; }
  else if (e < 8650752ull) { src = w10; dst = base + 8388608;  le = e - 8388608;  prows = 0x7fffffffu; }
  else if (e < 8912896ull) { src = w11; dst = base + 8650752;  le = e - 8650752;  prows = 0x7fffffffu; }
  else if (e < 9175040ull) { src = w30; dst = base + 8912896;  le = e - 8912896;  prows = 0x7fffffffu; }
  else if (e < 9437184ull) { src = w31; dst = base + 9175040;  le = e - 9175040;  prows = 0x7fffffffu; }
  else if (e < 9699328ull) { src = wo;  dst = base + 9437184;  le = e - 9437184;  prows = 0x7fffffffu; }
  else if (e < 9764864ull) { src = w20; dst = base + 9699328;  le = e - 9699328;  prows = 124; }
  else                     { src = w21; dst = base + 9764864;  le = e - 9764864;  prows = 244; }
  float4 val = make_float4(0.f, 0.f, 0.f, 0.f);
  if ((unsigned)(le >> 9) < prows) val = *(const float4*)(src + le);
  unsigned p0 = (unsigned)f2bf(val.x) | ((unsigned)f2bf(val.y) << 16);
  unsigned p1 = (unsigned)f2bf(val.z) | ((unsigned)f2bf(val.w) << 16);
  *(uint2*)(dst + le) = make_uint2(p0, p1);
}

// ---------------------------------------------------------------------------
// m97-structure GEMM core (round-2 verbatim)
// ---------------------------------------------------------------------------
template <int OUTBF>
__device__ __forceinline__ void gemm_core(
    const u16* __restrict__ A, int lda, const u16* __restrict__ W, int ldw,
    float* __restrict__ Cf, u16* __restrict__ Cb, int ldc, int relu,
    u16* lA, u16* lB) {
  const int tid = threadIdx.x;
  const int wave = tid >> 6, lane = tid & 63;
  const int wm = (wave >> 1) * 64, wn = (wave & 1) * 64;
  const int lr = lane & 15, kq = (lane >> 4) * 8;
  const int sr = lane >> 2, sc = (lane & 3) * 8;

  floatx4 acc[4][4];
#pragma unroll
  for (int i = 0; i < 4; ++i)
#pragma unroll
    for (int j = 0; j < 4; ++j) acc[i][j] = (floatx4){0.f, 0.f, 0.f, 0.f};

  const u16* ga0 = A + (u64)(wave * 32 + sr) * lda + sc;
  const u16* ga1 = A + (u64)(wave * 32 + 16 + sr) * lda + sc;
  const u16* gb0 = W + (u64)(wave * 32 + sr) * ldw + sc;
  const u16* gb1 = W + (u64)(wave * 32 + 16 + sr) * ldw + sc;
  u16* la0 = lA + (wave * 32) * 32;
  u16* la1 = lA + (wave * 32 + 16) * 32;
  u16* lb0 = lB + (wave * 32) * 32;
  u16* lb1 = lB + (wave * 32 + 16) * 32;

  for (int k0 = 0; k0 < 512; k0 += 32) {
    __syncthreads();
    gl16(ga0 + k0, la0);
    gl16(ga1 + k0, la1);
    gl16(gb0 + k0, lb0);
    gl16(gb1 + k0, lb1);
    __syncthreads();
    shortx8 af[4], bf8[4];
#pragma unroll
    for (int i = 0; i < 4; ++i) {
      af[i] = *(const shortx8*)&lA[(wm + i * 16 + lr) * 32 + kq];
      bf8[i] = *(const shortx8*)&lB[(wn + i * 16 + lr) * 32 + kq];
    }
#pragma unroll
    for (int mi = 0; mi < 4; ++mi)
#pragma unroll
      for (int ni = 0; ni < 4; ++ni)
        acc[mi][ni] = __builtin_amdgcn_mfma_f32_16x16x32_bf16(af[mi], bf8[ni], acc[mi][ni], 0, 0, 0);
  }
  const int er = wm + (lane >> 4) * 4;
  const int ec = wn + lr;
#pragma unroll
  for (int mi = 0; mi < 4; ++mi)
#pragma unroll
    for (int ni = 0; ni < 4; ++ni)
#pragma unroll
      for (int r = 0; r < 4; ++r) {
        float vv = acc[mi][ni][r];
        if (relu) vv = fmaxf(vv, 0.f);
        u64 off = (u64)(er + mi * 16 + r) * (u64)ldc + (u64)(ec + ni * 16);
        if (OUTBF) Cb[off] = f2bf(vv);
        else Cf[off] = vv;
      }
}

// fused q/v projection: grid (128, 8). x<64 -> q-half (relu), else v-half.
__global__ __launch_bounds__(256, 2) void k_qv(
    const u16* __restrict__ qb, const u16* __restrict__ vb,
    const u16* __restrict__ w1, const u16* __restrict__ w3,
    u16* __restrict__ rq, u16* __restrict__ vc) {
  __shared__ __align__(16) u16 lA[128 * 32];
  __shared__ __align__(16) u16 lB[128 * 32];
  const int bx = blockIdx.x, bn = blockIdx.y * 128;
  const bool isq = bx < 64;
  const int am = (isq ? bx : bx - 64) * 128;
  const u16* A = (isq ? qb : vb) + (u64)am * 512;
  const u16* W = (isq ? w1 : w3) + (u64)bn * 512;
  u16* Cb = (isq ? rq : vc) + (u64)am * 1024 + bn;
  gemm_core<1>(A, 512, W, 512, nullptr, Cb, 1024, isq ? 1 : 0, lA, lB);
}

// fused logits for both scales: grid (64, 3).
__global__ __launch_bounds__(256, 2) void k_logits(
    const u16* __restrict__ rq, const u16* __restrict__ w20,
    const u16* __restrict__ w21, float* __restrict__ lg) {
  __shared__ __align__(16) u16 lA[128 * 32];
  __shared__ __align__(16) u16 lB[128 * 32];
  const int am = blockIdx.x * 128;
  const int y = blockIdx.y;
  const u16* A = rq + (u64)am * 1024 + (y == 0 ? 0 : 512);
  const u16* W = (y == 0) ? w20 : (w21 + (u64)(y - 1) * 128 * 512);
  float* Cf = lg + (u64)am * 384 + y * 128;
  gemm_core<0>(A, 1024, W, 512, Cf, nullptr, 384, 0, lA, lB);
}

// final projection: grid (64, 4), fp32 out.
__global__ __launch_bounds__(256, 2) void k_final(
    const u16* __restrict__ xb, const u16* __restrict__ wo,
    float* __restrict__ out) {
  __shared__ __align__(16) u16 lA[128 * 32];
  __shared__ __align__(16) u16 lB[128 * 32];
  const int am = blockIdx.x * 128, bn = blockIdx.y * 128;
  gemm_core<0>(xb + (u64)am * 512, 512, wo + (u64)bn * 512, 512,
               out + (u64)am * 512 + bn, nullptr, 512, 0, lA, lB);
}

// ---------------------------------------------------------------------------
// MFMA attention, round-9: d-SPLIT for residency. Each block owns 64 of the
// 128 head-dims (dh = 0/1): vT halves to [64 d][VLDT], LDS 37.1 KB -> 4
// blocks/CU, grid 1024 = 4/CU; o/acc halve (nt < 4). launch_bounds (256,2)
// caps VGPR at 128 so 16 waves/CU actually materialize (spill signature =
// WRITE_SIZE balloon; watched). exp/es16 work duplicates across the dh pair
// (cheap). Numerics per output element identical to rounds 6-8.
// ---------------------------------------------------------------------------
#define VLDT 136
#define ESL 152

template <int CS, int CHUNK>
__device__ __forceinline__ void attn_mfma_pass(
    const float* __restrict__ lg,   // pre-offset to scale+head col base, row stride 384
    const u16* __restrict__ vbh,    // vcat + scale*512 + h*128 + dh*64, row stride 1024
    int bb, int t0, float swv,
    u16* vT, u16* es16, float* invsum, floatx4 (&o)[4]) {
  constexpr int HALF = (CS - 1) / 2;
  constexpr int NW = 64 + CS - 1;  // valid window rows (94 / 124)
  const int tid = threadIdx.x;
  const int wave = tid >> 6, lane = tid & 63;
  const int lr = lane & 15, kq = (lane >> 4) * 8;

  __syncthreads();  // prior consumers done with vT/es16/invsum

  // stage V-window (64 d-cols) transposed+swizzled; coalesced 128B segments.
#pragma unroll
  for (int it = 0; it < 4; ++it) {
    int idx = it * 256 + tid;
    int r = idx >> 3;              // 0..127
    int dl8 = (idx & 7) * 8;       // 0..56 (local d chunk)
    int t = t0 + r - HALF;
    uint4 u = make_uint4(0u, 0u, 0u, 0u);
    if (r < NW && t >= 0 && t < 2048)
      u = *(const uint4*)&vbh[(u64)(bb + t) * 1024 + dl8];
    int sb = (((r >> 3) ^ ((dl8 >> 3) & 7)) << 3) + (r & 7);
    u16* wp = &vT[dl8 * VLDT + sb];
    const u16* us = (const u16*)&u;
#pragma unroll
    for (int j = 0; j < 8; ++j) wp[j * VLDT] = us[j];
  }

  // exp (chunked global reads) + complement zeros + quad row-sum via shfl
  {
    int tt = tid >> 2, qq = tid & 3;
    u16* row = es16 + tt * ESL;
    const int lo = tt, hi = tt + CS;
#pragma unroll
    for (int j = 0; j < 32; ++j) {
      int x = qq * 32 + j;
      if (x < lo || x >= hi) row[x] = 0;
    }
    const float* lrow = lg + (u64)(bb + t0 + tt) * 384 + qq * CHUNK;
    float ps = 0.f;
#pragma unroll
    for (int j = 0; j < CHUNK; ++j) {
      int c = qq * CHUNK + j;
      if (c < CS) {
        float ev = __expf(lrow[j]);
        row[lo + c] = f2bf(ev);
        ps += ev;
      }
    }
    ps += __shfl_xor(ps, 1, 64);
    ps += __shfl_xor(ps, 2, 64);
    if (qq == 0) invsum[tt] = swv / ps;
  }
  __syncthreads();

  // MFMA: wave w owns output rows w*16..w*16+15; band limits k-blocks.
  const int kb_lo = (wave * 16) >> 5;
  const int kb_hi = (wave * 16 + 15 + CS - 1) >> 5;
  floatx4 acc[4];
#pragma unroll
  for (int nt = 0; nt < 4; ++nt) acc[nt] = (floatx4){0.f, 0.f, 0.f, 0.f};
  for (int kb = kb_lo; kb <= kb_hi; ++kb) {
    shortx8 af = *(const shortx8*)&es16[(wave * 16 + lr) * ESL + kb * 32 + kq];
    int rb8 = kb * 4 + (lane >> 4);
#pragma unroll
    for (int nt = 0; nt < 4; ++nt) {
      int d_row = nt * 16 + lr;   // 0..63 local d
      int blk = (rb8 ^ ((d_row >> 3) & 7)) << 3;
      shortx8 bf8 = *(const shortx8*)&vT[d_row * VLDT + blk];
      acc[nt] = __builtin_amdgcn_mfma_f32_16x16x32_bf16(af, bf8, acc[nt], 0, 0, 0);
    }
  }
  // fold swv/rowsum, accumulate into persistent o (C-layout rows)
  float invs[4];
#pragma unroll
  for (int rr = 0; rr < 4; ++rr)
    invs[rr] = invsum[wave * 16 + (lane >> 4) * 4 + rr];
#pragma unroll
  for (int nt = 0; nt < 4; ++nt)
#pragma unroll
    for (int rr = 0; rr < 4; ++rr) o[nt][rr] += acc[nt][rr] * invs[rr];
}

__global__ __launch_bounds__(256, 2) void k_attn4(
    const float* __restrict__ lg, const u16* __restrict__ vcat,
    const float* __restrict__ swp, u16* __restrict__ xbw) {
  __shared__ __align__(16) u16 vT[64 * VLDT];
  __shared__ __align__(16) u16 es16[64 * ESL];
  __shared__ float invsum[64];
  const int tid = threadIdx.x;
  const int wave = tid >> 6, lane = tid & 63;
  const int lr = lane & 15;
  const int t0 = blockIdx.x * 64;
  const int h = blockIdx.y >> 1, dh = blockIdx.y & 1;
  const int b = blockIdx.z;
  const int bb = b * 2048;
  const int m0 = bb + t0;

  float a0 = swp[0], a1 = swp[1];
  float mx = fmaxf(a0, a1);
  float e0 = __expf(a0 - mx), e1 = __expf(a1 - mx);
  float inv = 1.f / (e0 + e1);

  floatx4 o[4];
#pragma unroll
  for (int nt = 0; nt < 4; ++nt) o[nt] = (floatx4){0.f, 0.f, 0.f, 0.f};

  attn_mfma_pass<31, 8>(lg + h * 31, vcat + h * 128 + dh * 64,
                        bb, t0, e0 * inv, vT, es16, invsum, o);
  attn_mfma_pass<61, 16>(lg + 128 + h * 61, vcat + 512 + h * 128 + dh * 64,
                         bb, t0, e1 * inv, vT, es16, invsum, o);

  // epilogue: stage bf16 output half-tile in es16 (reuse), coalesced stores
  __syncthreads();
#pragma unroll
  for (int nt = 0; nt < 4; ++nt)
#pragma unroll
    for (int rr = 0; rr < 4; ++rr) {
      int trow = wave * 16 + (lane >> 4) * 4 + rr;
      es16[trow * ESL + nt * 16 + lr] = f2bf(o[nt][rr]);
    }
  __syncthreads();
#pragma unroll
  for (int rep = 0; rep < 2; ++rep) {
    int idx = rep * 256 + tid;
    int trow = idx >> 3;            // 0..63
    int col8 = (idx & 7) * 8;       // 0..56
    uint4 u = *(const uint4*)&es16[trow * ESL + col8];
    *(uint4*)&xbw[(u64)(m0 + trow) * 512 + h * 128 + dh * 64 + col8] = u;
  }
}

// ---------------------------------------------------------------------------
extern "C" void kernel_launch(void* const* d_in, const int* in_sizes, int n_in,
                              void* d_out, int out_size, void* d_ws, size_t ws_size,
                              hipStream_t stream) {
  const float* q   = (const float*)d_in[0];
  const float* v   = (const float*)d_in[2];
  const float* w10 = (const float*)d_in[3];
  const float* w11 = (const float*)d_in[4];
  const float* w20 = (const float*)d_in[5];
  const float* w21 = (const float*)d_in[6];
  const float* w30 = (const float*)d_in[7];
  const float* w31 = (const float*)d_in[8];
  const float* sw  = (const float*)d_in[9];
  const float* wo  = (const float*)d_in[10];
  float* out = (float*)d_out;

  u16* base  = (u16*)d_ws;
  u16* qb    = base;
  u16* vb    = base + 4194304;
  u16* w1cat = base + 8388608;
  u16* w3cat = base + 8912896;
  u16* wob   = base + 9437184;
  u16* w2b0  = base + 9699328;
  u16* w2b1  = base + 9764864;
  char* fb = (char*)d_ws + 19791872;
  float* logitsC = (float*)fb;            // [8192][384]
  u16* rqcat = (u16*)(logitsC + 3145728); // [8192][1024]
  u16* vcat  = rqcat + 8388608;           // [8192][1024]
  u16* xb    = vcat + 8388608;            // [8192][512]
  // total ws use: 74,317,824 bytes

  convert_all<<<dim3(9664), dim3(256), 0, stream>>>(q, v, w10, w11, w30, w31, wo, w20, w21, base);

  dim3 blk(256);
  k_qv<<<dim3(128, 8), blk, 0, stream>>>(qb, vb, w1cat, w3cat, rqcat, vcat);
  k_logits<<<dim3(64, 3), blk, 0, stream>>>(rqcat, w2b0, w2b1, logitsC);
  k_attn4<<<dim3(32, 8, 4), blk, 0, stream>>>(logitsC, vcat, sw, xb);
  k_final<<<dim3(64, 4), blk, 0, stream>>>(xb, wob, out);
}